// Round 8
// baseline (1334.786 us; speedup 1.0000x reference)
//
#include <hip/hip_runtime.h>
#include <math.h>

#define N_STEPS 50
#define DT 0.02f

typedef __attribute__((ext_vector_type(8))) short    bf16x8;
typedef __attribute__((ext_vector_type(4))) float    f32x4;
typedef __attribute__((ext_vector_type(4))) unsigned u32x4;

// RNE float->bf16 (software, setup-time only)
__device__ inline unsigned f2bf(float f) {
    unsigned u = __builtin_bit_cast(unsigned, f);
    return ((u + 0x7FFFu + ((u >> 16) & 1u)) >> 16);
}
__device__ inline unsigned pk2(float lo, float hi) {
    return (f2bf(lo) & 0xFFFFu) | (f2bf(hi) << 16);
}
// fast per-step packed convert (1 instr)
__device__ inline unsigned cvtpk(float lo, float hi) {
    unsigned r;
    asm("v_cvt_pk_bf16_f32 %0, %1, %2" : "=v"(r) : "v"(lo), "v"(hi));
    return r;
}
__device__ inline bf16x8 mk8(unsigned a, unsigned b, unsigned cc, unsigned d) {
    u32x4 t; t.x = a; t.y = b; t.z = cc; t.w = d;
    return __builtin_bit_cast(bf16x8, t);
}

// Block = 128 threads = 2 waves = one path-pair group of 64 paths.
//   wave 0 (net=0): z-net for paths [base, base+64)
//   wave 1 (net=1): q-net for same paths
// MFMA 16x16x32 bf16 MLP with all weights resident in VGPRs.
//
// Round-8 change vs round 7: the round-7 build needed ~206 VGPRs against a
// 128 cap -> ~70 regs of per-step scratch spill (WRITE_SIZE 10.3 MB, the
// stall source behind VALUBusy 43%). Fixes, all bitwise-neutral:
//   - xf built per-t4 inside the L1 loop (16 -> 4 live regs)
//   - L2 restructured t4-outer: one acc f32x4 + one hf pair live
//     (48 -> 12 regs); per-accumulator MFMA order and p[t4] (mt,r)
//     accumulation order are IDENTICAL to round 7 -> same bits out.
//   - launch_bounds(128,3): cap ~170 VGPRs, fits the ~160 live set with
//     zero spill, guarantees 3 waves/SIMD residency.
__global__ __launch_bounds__(128, 3) void bsde_kernel(
    const float* __restrict__ y0v, const float* __restrict__ Y0v,
    const float* __restrict__ qW1, const float* __restrict__ qb1,
    const float* __restrict__ qW2, const float* __restrict__ qb2,
    const float* __restrict__ qW3, const float* __restrict__ qb3,
    const float* __restrict__ zW1, const float* __restrict__ zb1,
    const float* __restrict__ zW2, const float* __restrict__ zb2,
    const float* __restrict__ zW3, const float* __restrict__ zb3,
    const float* __restrict__ dW,
    float* __restrict__ out, int B)
{
    const int lane = threadIdx.x & 63;
    const int net  = threadIdx.x >> 6;        // 0 = z-net wave, 1 = q-net wave
    const int c    = lane & 15;               // path-col within a 16-tile
    const int g    = lane >> 4;               // lane group
    const int p    = blockIdx.x * 64 + lane;  // this lane's path

    __shared__ unsigned short ex[2][4096];    // per-wave 8KB h1 exchange tile
    __shared__ float qbuf[2][64];

    const float* W1 = net ? qW1 : zW1;
    const float* b1 = net ? qb1 : zb1;
    const float* W2 = net ? qW2 : zW2;
    const float* b2 = net ? qb2 : zb2;
    const float* W3 = net ? qW3 : zW3;
    const float* b3 = net ? qb3 : zb3;

    // ---------------- one-time weight fragment preload ----------------
    bf16x8 w1f[4];                            // A-frags, L1 (W1 rows 0..3 + b1)
#pragma unroll
    for (int mt = 0; mt < 4; ++mt) {
        const int h = 16 * mt + c;
        unsigned d0 = 0, d1 = 0, d2 = 0;
        if (g == 0) {
            d0 = pk2(W1[0 * 64 + h], W1[1 * 64 + h]);   // k0=t, k1=y0
            d1 = pk2(W1[2 * 64 + h], W1[3 * 64 + h]);   // k2=y1, k3=y2
            d2 = f2bf(b1[h]) & 0xFFFFu;                 // k4=1-const row
        }
        w1f[mt] = mk8(d0, d1, d2, 0);
    }

    bf16x8 w2f[4][2];                         // A-frags, L2 (W2 transposed)
#pragma unroll
    for (int mt = 0; mt < 4; ++mt)
#pragma unroll
    for (int kt = 0; kt < 2; ++kt) {
        const int h = 16 * mt + c;            // h2 output index (M)
        const int k0 = 32 * kt + 8 * g;       // h1 input index base (K)
        unsigned d0 = pk2(W2[(k0 + 0) * 64 + h], W2[(k0 + 1) * 64 + h]);
        unsigned d1 = pk2(W2[(k0 + 2) * 64 + h], W2[(k0 + 3) * 64 + h]);
        unsigned d2 = pk2(W2[(k0 + 4) * 64 + h], W2[(k0 + 5) * 64 + h]);
        unsigned d3 = pk2(W2[(k0 + 6) * 64 + h], W2[(k0 + 7) * 64 + h]);
        w2f[mt][kt] = mk8(d0, d1, d2, d3);
    }

    f32x4 b2v[4];                             // b2 in C-layout (acc init)
#pragma unroll
    for (int mt = 0; mt < 4; ++mt)
#pragma unroll
    for (int r = 0; r < 4; ++r)
        b2v[mt][r] = b2[16 * mt + 4 * g + r];

    float w3v[3][4][4];                       // W3 in C-layout per lane
#pragma unroll
    for (int mt = 0; mt < 4; ++mt)
#pragma unroll
    for (int r = 0; r < 4; ++r) {
        const int h = 16 * mt + 4 * g + r;
        if (net) { w3v[0][mt][r] = W3[h];       w3v[1][mt][r] = 0.f;         w3v[2][mt][r] = 0.f; }
        else     { w3v[0][mt][r] = W3[3*h + 0]; w3v[1][mt][r] = W3[3*h + 1]; w3v[2][mt][r] = W3[3*h + 2]; }
    }

    char* exn = (char*)&ex[net][0];
    const int sw = (c & 7) << 4;              // LDS XOR swizzle key
    const unsigned jp2c = (g == 0) ? 0x3F80u : 0u;   // bf16(1.0) in k=4 slot

    const float sqrt_dt = sqrtf(DT);
    float y0 = y0v[0], y1 = y0v[1], y2 = y0v[2];
    float Y  = Y0v[0];

    for (int n = 0; n < N_STEPS; ++n) {
        const float t  = (float)n * DT;
        const int   bu = n & 1;

        const size_t idx = ((size_t)n * (size_t)B + (size_t)p) * 3;
        const float dr0 = dW[idx + 0];
        const float dr1 = dW[idx + 1];
        const float dr2 = dW[idx + 2];

        // ---- L1: per-t4 build B1 frag, 4 MFMA, relu+pack+swizzled write ----
#pragma unroll
        for (int t4 = 0; t4 < 4; ++t4) {
            const int src = 16 * t4 + c;
            const float s0 = __shfl(y0, src, 64);
            const float s1 = __shfl(y1, src, 64);
            const float s2 = __shfl(y2, src, 64);
            const unsigned a = cvtpk(t,  s0);
            const unsigned b = cvtpk(s1, s2);
            const bf16x8 xf = mk8((g == 0) ? a : 0u, (g == 0) ? b : 0u, jp2c, 0u);
#pragma unroll
            for (int mt = 0; mt < 4; ++mt) {
                f32x4 c1 = __builtin_amdgcn_mfma_f32_16x16x32_bf16(
                    w1f[mt], xf, (f32x4){0.f, 0.f, 0.f, 0.f}, 0, 0, 0);
                const unsigned lo = cvtpk(fmaxf(c1[0], 0.f), fmaxf(c1[1], 0.f));
                const unsigned hi = cvtpk(fmaxf(c1[2], 0.f), fmaxf(c1[3], 0.f));
                const int off = (((16 * t4 + c) * 128) + 32 * mt + 8 * g) ^ sw;
                *(unsigned long long*)(exn + off) =
                    ((unsigned long long)hi << 32) | (unsigned long long)lo;
            }
        }

        // ---- L2 + L3 partials, t4-outer (minimal live registers) ----
        float p0[4] = {0.f, 0.f, 0.f, 0.f};
        float p1[4] = {0.f, 0.f, 0.f, 0.f};
        float p2[4] = {0.f, 0.f, 0.f, 0.f};
#pragma unroll
        for (int t4 = 0; t4 < 4; ++t4) {
            const int rb = ((16 * t4 + c) * 128) + 16 * g;
            const bf16x8 hf0 = *(const bf16x8*)(exn + ((rb +  0) ^ sw));
            const bf16x8 hf1 = *(const bf16x8*)(exn + ((rb + 64) ^ sw));
#pragma unroll
            for (int mt = 0; mt < 4; ++mt) {
                f32x4 acc = __builtin_amdgcn_mfma_f32_16x16x32_bf16(
                    w2f[mt][0], hf0, b2v[mt], 0, 0, 0);
                acc = __builtin_amdgcn_mfma_f32_16x16x32_bf16(
                    w2f[mt][1], hf1, acc, 0, 0, 0);
#pragma unroll
                for (int r = 0; r < 4; ++r) {
                    const float h = fmaxf(acc[r], 0.f);
                    p0[t4] = fmaf(h, w3v[0][mt][r], p0[t4]);
                    if (net == 0) {
                        p1[t4] = fmaf(h, w3v[1][mt][r], p1[t4]);
                        p2[t4] = fmaf(h, w3v[2][mt][r], p2[t4]);
                    }
                }
            }
        }

        // ---- cross-lane reduce: land each path's outputs on its lane ----
        float out0, oz1 = 0.f, oz2 = 0.f;
        {
            float r4[4];
#pragma unroll
            for (int t4 = 0; t4 < 4; ++t4) {
                float v = p0[t4];
                v += __shfl_xor(v, 16, 64);
                v += __shfl_xor(v, 32, 64);
                r4[t4] = v;
            }
            float pick = r4[0];
            pick = (g == 1) ? r4[1] : pick;
            pick = (g == 2) ? r4[2] : pick;
            pick = (g == 3) ? r4[3] : pick;
            out0 = pick + b3[0];
        }
        if (net == 0) {
            float r4[4];
#pragma unroll
            for (int t4 = 0; t4 < 4; ++t4) {
                float v = p1[t4];
                v += __shfl_xor(v, 16, 64);
                v += __shfl_xor(v, 32, 64);
                r4[t4] = v;
            }
            float pick = r4[0];
            pick = (g == 1) ? r4[1] : pick;
            pick = (g == 2) ? r4[2] : pick;
            pick = (g == 3) ? r4[3] : pick;
            oz1 = pick + b3[1];
#pragma unroll
            for (int t4 = 0; t4 < 4; ++t4) {
                float v = p2[t4];
                v += __shfl_xor(v, 16, 64);
                v += __shfl_xor(v, 32, 64);
                r4[t4] = v;
            }
            pick = r4[0];
            pick = (g == 1) ? r4[1] : pick;
            pick = (g == 2) ? r4[2] : pick;
            pick = (g == 3) ? r4[3] : pick;
            oz2 = pick + b3[2];
        }

        // ---- one-way q exchange (q-wave -> z-wave), 1 barrier/step ----
        if (net == 1) qbuf[bu][lane] = out0;
        __syncthreads();
        const float qq = net ? out0 : qbuf[bu][lane];

        // ---- SDE update (fp32, same expression order as rounds 0-7) ----
        const float dw0 = dr0 * sqrt_dt;
        const float dw1 = dr1 * sqrt_dt;
        const float dw2 = dr2 * sqrt_dt;

        if (net == 0) {
            const float f = 0.5f * qq * qq;
            Y = Y - f * DT + (out0 * dw0 + oz1 * dw1 + oz2 * dw2);
        }

        const float s0 = 0.2f + 0.1f * tanhf(y0);
        const float s1 = 0.2f + 0.1f * tanhf(y1);
        const float s2 = 0.2f + 0.1f * tanhf(y2);
        y0 = y0 + (qq - y0) * DT + s0 * dw0;
        y1 = y1 + (qq - y1) * DT + s1 * dw1;
        y2 = y2 + (qq - y2) * DT + s2 * dw2;
    }

    // Only the z-waves contribute; each path counted once.
    if (net == 0) {
        const float term = y0 * y0 + y1 * y1 + y2 * y2;
        const float d    = Y - term;
        float val = d * d;
#pragma unroll
        for (int off = 32; off > 0; off >>= 1)
            val += __shfl_down(val, off, 64);
        if (lane == 0)
            atomicAdd(out, val * (1.0f / (float)B));
    }
}

extern "C" void kernel_launch(void* const* d_in, const int* in_sizes, int n_in,
                              void* d_out, int out_size, void* d_ws, size_t ws_size,
                              hipStream_t stream) {
    const float* y0  = (const float*)d_in[0];
    const float* Y0  = (const float*)d_in[1];
    const float* qW1 = (const float*)d_in[2];
    const float* qb1 = (const float*)d_in[3];
    const float* qW2 = (const float*)d_in[4];
    const float* qb2 = (const float*)d_in[5];
    const float* qW3 = (const float*)d_in[6];
    const float* qb3 = (const float*)d_in[7];
    const float* zW1 = (const float*)d_in[8];
    const float* zb1 = (const float*)d_in[9];
    const float* zW2 = (const float*)d_in[10];
    const float* zb2 = (const float*)d_in[11];
    const float* zW3 = (const float*)d_in[12];
    const float* zb3 = (const float*)d_in[13];
    const float* dW  = (const float*)d_in[14];

    const int B = in_sizes[14] / (N_STEPS * 3);   // 131072
    float* out = (float*)d_out;

    hipMemsetAsync(out, 0, sizeof(float), stream);

    const int threads = 128;                       // 2 waves: z-net + q-net
    const int blocks  = B / 64;                    // 2048 blocks, 64 paths each
    bsde_kernel<<<blocks, threads, 0, stream>>>(
        y0, Y0, qW1, qb1, qW2, qb2, qW3, qb3,
        zW1, zb1, zW2, zb2, zW3, zb3, dW, out, B);
}

// Round 9
// 445.544 us; speedup vs baseline: 2.9959x; 2.9959x over previous
//
#include <hip/hip_runtime.h>
#include <math.h>

#define N_STEPS 50
#define DT 0.02f

typedef __attribute__((ext_vector_type(8))) short    bf16x8;
typedef __attribute__((ext_vector_type(4))) float    f32x4;
typedef __attribute__((ext_vector_type(4))) unsigned u32x4;

// RNE float->bf16 (software, setup-time only)
__device__ inline unsigned f2bf(float f) {
    unsigned u = __builtin_bit_cast(unsigned, f);
    return ((u + 0x7FFFu + ((u >> 16) & 1u)) >> 16);
}
__device__ inline unsigned pk2(float lo, float hi) {
    return (f2bf(lo) & 0xFFFFu) | (f2bf(hi) << 16);
}
// fast per-step packed convert (1 instr)
__device__ inline unsigned cvtpk(float lo, float hi) {
    unsigned r;
    asm("v_cvt_pk_bf16_f32 %0, %1, %2" : "=v"(r) : "v"(lo), "v"(hi));
    return r;
}
__device__ inline bf16x8 mk8(unsigned a, unsigned b, unsigned cc, unsigned d) {
    u32x4 t; t.x = a; t.y = b; t.z = cc; t.w = d;
    return __builtin_bit_cast(bf16x8, t);
}

// Block = 128 threads = 2 waves = one path-pair group of 64 paths.
//   wave 0 (net=0): z-net for paths [base, base+64)
//   wave 1 (net=1): q-net for same paths
// MFMA 16x16x32 bf16 MLP, W1/W2 fragments resident in VGPRs.
//
// Round-9 change vs round 8: round 8's launch_bounds(128,3) made the
// allocator collapse to 84 VGPRs and spill the weight fragments to
// scratch -- FETCH_SIZE 2 GB/dispatch of spill-RELOAD traffic. Fix:
//   - W3 moved out of registers into a one-time 2 KB LDS table w3t
//     (f32x4 per h2-row; 4 addrs/wave 64 B apart = 2-way conflict = free).
//     48 fewer live VGPRs; same fp32 bits, same fma order -> bitwise
//     identical output.
//   - launch_bounds back to (128,2) (cap 256): live set ~120 fits with
//     zero spill.
__global__ __launch_bounds__(128, 2) void bsde_kernel(
    const float* __restrict__ y0v, const float* __restrict__ Y0v,
    const float* __restrict__ qW1, const float* __restrict__ qb1,
    const float* __restrict__ qW2, const float* __restrict__ qb2,
    const float* __restrict__ qW3, const float* __restrict__ qb3,
    const float* __restrict__ zW1, const float* __restrict__ zb1,
    const float* __restrict__ zW2, const float* __restrict__ zb2,
    const float* __restrict__ zW3, const float* __restrict__ zb3,
    const float* __restrict__ dW,
    float* __restrict__ out, int B)
{
    const int lane = threadIdx.x & 63;
    const int net  = threadIdx.x >> 6;        // 0 = z-net wave, 1 = q-net wave
    const int c    = lane & 15;               // path-col within a 16-tile
    const int g    = lane >> 4;               // lane group
    const int p    = blockIdx.x * 64 + lane;  // this lane's path

    __shared__ unsigned short ex[2][4096];    // per-wave 8KB h1 exchange tile
    __shared__ float qbuf[2][64];
    __shared__ f32x4 w3t[2][64];              // W3 in C-layout, one-time

    const float* W1 = net ? qW1 : zW1;
    const float* b1 = net ? qb1 : zb1;
    const float* W2 = net ? qW2 : zW2;
    const float* b2 = net ? qb2 : zb2;
    const float* W3 = net ? qW3 : zW3;
    const float* b3 = net ? qb3 : zb3;

    // ---------------- one-time W3 -> LDS table ----------------
    if (net) w3t[1][lane] = (f32x4){W3[lane], 0.f, 0.f, 0.f};
    else     w3t[0][lane] = (f32x4){W3[3*lane+0], W3[3*lane+1], W3[3*lane+2], 0.f};

    // ---------------- one-time weight fragment preload ----------------
    bf16x8 w1f[4];                            // A-frags, L1 (W1 rows 0..3 + b1)
#pragma unroll
    for (int mt = 0; mt < 4; ++mt) {
        const int h = 16 * mt + c;
        unsigned d0 = 0, d1 = 0, d2 = 0;
        if (g == 0) {
            d0 = pk2(W1[0 * 64 + h], W1[1 * 64 + h]);   // k0=t, k1=y0
            d1 = pk2(W1[2 * 64 + h], W1[3 * 64 + h]);   // k2=y1, k3=y2
            d2 = f2bf(b1[h]) & 0xFFFFu;                 // k4=1-const row
        }
        w1f[mt] = mk8(d0, d1, d2, 0);
    }

    bf16x8 w2f[4][2];                         // A-frags, L2 (W2 transposed)
#pragma unroll
    for (int mt = 0; mt < 4; ++mt)
#pragma unroll
    for (int kt = 0; kt < 2; ++kt) {
        const int h = 16 * mt + c;            // h2 output index (M)
        const int k0 = 32 * kt + 8 * g;       // h1 input index base (K)
        unsigned d0 = pk2(W2[(k0 + 0) * 64 + h], W2[(k0 + 1) * 64 + h]);
        unsigned d1 = pk2(W2[(k0 + 2) * 64 + h], W2[(k0 + 3) * 64 + h]);
        unsigned d2 = pk2(W2[(k0 + 4) * 64 + h], W2[(k0 + 5) * 64 + h]);
        unsigned d3 = pk2(W2[(k0 + 6) * 64 + h], W2[(k0 + 7) * 64 + h]);
        w2f[mt][kt] = mk8(d0, d1, d2, d3);
    }

    f32x4 b2v[4];                             // b2 in C-layout (acc init)
#pragma unroll
    for (int mt = 0; mt < 4; ++mt)
#pragma unroll
    for (int r = 0; r < 4; ++r)
        b2v[mt][r] = b2[16 * mt + 4 * g + r];

    __syncthreads();                          // w3t visible

    char* exn = (char*)&ex[net][0];
    const int sw = (c & 7) << 4;              // LDS XOR swizzle key
    const unsigned jp2c = (g == 0) ? 0x3F80u : 0u;   // bf16(1.0) in k=4 slot

    const float sqrt_dt = sqrtf(DT);
    float y0 = y0v[0], y1 = y0v[1], y2 = y0v[2];
    float Y  = Y0v[0];

    for (int n = 0; n < N_STEPS; ++n) {
        const float t  = (float)n * DT;
        const int   bu = n & 1;

        const size_t idx = ((size_t)n * (size_t)B + (size_t)p) * 3;
        const float dr0 = dW[idx + 0];
        const float dr1 = dW[idx + 1];
        const float dr2 = dW[idx + 2];

        // ---- L1: per-t4 build B1 frag, 4 MFMA, relu+pack+swizzled write ----
#pragma unroll
        for (int t4 = 0; t4 < 4; ++t4) {
            const int src = 16 * t4 + c;
            const float s0 = __shfl(y0, src, 64);
            const float s1 = __shfl(y1, src, 64);
            const float s2 = __shfl(y2, src, 64);
            const unsigned a = cvtpk(t,  s0);
            const unsigned b = cvtpk(s1, s2);
            const bf16x8 xf = mk8((g == 0) ? a : 0u, (g == 0) ? b : 0u, jp2c, 0u);
#pragma unroll
            for (int mt = 0; mt < 4; ++mt) {
                f32x4 c1 = __builtin_amdgcn_mfma_f32_16x16x32_bf16(
                    w1f[mt], xf, (f32x4){0.f, 0.f, 0.f, 0.f}, 0, 0, 0);
                const unsigned lo = cvtpk(fmaxf(c1[0], 0.f), fmaxf(c1[1], 0.f));
                const unsigned hi = cvtpk(fmaxf(c1[2], 0.f), fmaxf(c1[3], 0.f));
                const int off = (((16 * t4 + c) * 128) + 32 * mt + 8 * g) ^ sw;
                *(unsigned long long*)(exn + off) =
                    ((unsigned long long)hi << 32) | (unsigned long long)lo;
            }
        }

        // ---- L2 + L3 partials, t4-outer (minimal live registers) ----
        float p0[4] = {0.f, 0.f, 0.f, 0.f};
        float p1[4] = {0.f, 0.f, 0.f, 0.f};
        float p2[4] = {0.f, 0.f, 0.f, 0.f};
#pragma unroll
        for (int t4 = 0; t4 < 4; ++t4) {
            const int rb = ((16 * t4 + c) * 128) + 16 * g;
            const bf16x8 hf0 = *(const bf16x8*)(exn + ((rb +  0) ^ sw));
            const bf16x8 hf1 = *(const bf16x8*)(exn + ((rb + 64) ^ sw));
#pragma unroll
            for (int mt = 0; mt < 4; ++mt) {
                f32x4 acc = __builtin_amdgcn_mfma_f32_16x16x32_bf16(
                    w2f[mt][0], hf0, b2v[mt], 0, 0, 0);
                acc = __builtin_amdgcn_mfma_f32_16x16x32_bf16(
                    w2f[mt][1], hf1, acc, 0, 0, 0);
#pragma unroll
                for (int r = 0; r < 4; ++r) {
                    const float h = fmaxf(acc[r], 0.f);
                    const f32x4 w3r = w3t[net][16 * mt + 4 * g + r];
                    p0[t4] = fmaf(h, w3r[0], p0[t4]);
                    if (net == 0) {
                        p1[t4] = fmaf(h, w3r[1], p1[t4]);
                        p2[t4] = fmaf(h, w3r[2], p2[t4]);
                    }
                }
            }
        }

        // ---- cross-lane reduce: land each path's outputs on its lane ----
        float out0, oz1 = 0.f, oz2 = 0.f;
        {
            float r4[4];
#pragma unroll
            for (int t4 = 0; t4 < 4; ++t4) {
                float v = p0[t4];
                v += __shfl_xor(v, 16, 64);
                v += __shfl_xor(v, 32, 64);
                r4[t4] = v;
            }
            float pick = r4[0];
            pick = (g == 1) ? r4[1] : pick;
            pick = (g == 2) ? r4[2] : pick;
            pick = (g == 3) ? r4[3] : pick;
            out0 = pick + b3[0];
        }
        if (net == 0) {
            float r4[4];
#pragma unroll
            for (int t4 = 0; t4 < 4; ++t4) {
                float v = p1[t4];
                v += __shfl_xor(v, 16, 64);
                v += __shfl_xor(v, 32, 64);
                r4[t4] = v;
            }
            float pick = r4[0];
            pick = (g == 1) ? r4[1] : pick;
            pick = (g == 2) ? r4[2] : pick;
            pick = (g == 3) ? r4[3] : pick;
            oz1 = pick + b3[1];
#pragma unroll
            for (int t4 = 0; t4 < 4; ++t4) {
                float v = p2[t4];
                v += __shfl_xor(v, 16, 64);
                v += __shfl_xor(v, 32, 64);
                r4[t4] = v;
            }
            pick = r4[0];
            pick = (g == 1) ? r4[1] : pick;
            pick = (g == 2) ? r4[2] : pick;
            pick = (g == 3) ? r4[3] : pick;
            oz2 = pick + b3[2];
        }

        // ---- one-way q exchange (q-wave -> z-wave), 1 barrier/step ----
        if (net == 1) qbuf[bu][lane] = out0;
        __syncthreads();
        const float qq = net ? out0 : qbuf[bu][lane];

        // ---- SDE update (fp32, same expression order as rounds 0-8) ----
        const float dw0 = dr0 * sqrt_dt;
        const float dw1 = dr1 * sqrt_dt;
        const float dw2 = dr2 * sqrt_dt;

        if (net == 0) {
            const float f = 0.5f * qq * qq;
            Y = Y - f * DT + (out0 * dw0 + oz1 * dw1 + oz2 * dw2);
        }

        const float s0 = 0.2f + 0.1f * tanhf(y0);
        const float s1 = 0.2f + 0.1f * tanhf(y1);
        const float s2 = 0.2f + 0.1f * tanhf(y2);
        y0 = y0 + (qq - y0) * DT + s0 * dw0;
        y1 = y1 + (qq - y1) * DT + s1 * dw1;
        y2 = y2 + (qq - y2) * DT + s2 * dw2;
    }

    // Only the z-waves contribute; each path counted once.
    if (net == 0) {
        const float term = y0 * y0 + y1 * y1 + y2 * y2;
        const float d    = Y - term;
        float val = d * d;
#pragma unroll
        for (int off = 32; off > 0; off >>= 1)
            val += __shfl_down(val, off, 64);
        if (lane == 0)
            atomicAdd(out, val * (1.0f / (float)B));
    }
}

extern "C" void kernel_launch(void* const* d_in, const int* in_sizes, int n_in,
                              void* d_out, int out_size, void* d_ws, size_t ws_size,
                              hipStream_t stream) {
    const float* y0  = (const float*)d_in[0];
    const float* Y0  = (const float*)d_in[1];
    const float* qW1 = (const float*)d_in[2];
    const float* qb1 = (const float*)d_in[3];
    const float* qW2 = (const float*)d_in[4];
    const float* qb2 = (const float*)d_in[5];
    const float* qW3 = (const float*)d_in[6];
    const float* qb3 = (const float*)d_in[7];
    const float* zW1 = (const float*)d_in[8];
    const float* zb1 = (const float*)d_in[9];
    const float* zW2 = (const float*)d_in[10];
    const float* zb2 = (const float*)d_in[11];
    const float* zW3 = (const float*)d_in[12];
    const float* zb3 = (const float*)d_in[13];
    const float* dW  = (const float*)d_in[14];

    const int B = in_sizes[14] / (N_STEPS * 3);   // 131072
    float* out = (float*)d_out;

    hipMemsetAsync(out, 0, sizeof(float), stream);

    const int threads = 128;                       // 2 waves: z-net + q-net
    const int blocks  = B / 64;                    // 2048 blocks, 64 paths each
    bsde_kernel<<<blocks, threads, 0, stream>>>(
        y0, Y0, qW1, qb1, qW2, qb2, qW3, qb3,
        zW1, zb1, zW2, zb2, zW3, zb3, dW, out, B);
}